// Round 9
// baseline (184.980 us; speedup 1.0000x reference)
//
#include <hip/hip_runtime.h>
#include <hip/hip_bf16.h>

#define B_ 2
#define T_ 2048
#define H_ 1024
#define NH 16
#define HD 64

typedef __attribute__((ext_vector_type(8))) short bf16x8;
typedef __attribute__((ext_vector_type(4))) short bf16x4;
typedef __attribute__((ext_vector_type(4))) float f32x4;

#define ASYNC_COPY16(gptr, lptr)                                              \
    __builtin_amdgcn_global_load_lds(                                         \
        (const __attribute__((address_space(1))) void*)(gptr),                \
        (__attribute__((address_space(3))) void*)(lptr), 16, 0, 0)

#if __has_builtin(__builtin_amdgcn_exp2f)
#define EXP2(x) __builtin_amdgcn_exp2f(x)
#else
static __device__ inline float EXP2(float x) {
    float r;
    asm volatile("v_exp_f32 %0, %1" : "=v"(r) : "v"(x));
    return r;
}
#endif

static __device__ inline unsigned short f2bf(float f) {
    union { float f; unsigned u; } v; v.f = f;
    unsigned r = v.u + 0x7fff + ((v.u >> 16) & 1);
    return (unsigned short)(r >> 16);
}

static __device__ inline unsigned pkbf(float a, float b) {
    float2 t2; t2.x = a; t2.y = b;
    __hip_bfloat162 h = __float22bfloat162_rn(t2);
    union { __hip_bfloat162 h; unsigned u; } cv; cv.h = h;
    return cv.u;
}

static __device__ inline bf16x4 mk4(unsigned lo, unsigned hi) {
    union { bf16x4 v; unsigned u[2]; } cv;
    cv.u[0] = lo; cv.u[1] = hi;
    return cv.v;
}

static __device__ inline f32x4 zero4() {
    f32x4 z = {0.f, 0.f, 0.f, 0.f};
    return z;
}

#define LOG2E 1.44269504088896f

// ---------------------------------------------------------------------------
// blocks 0..8191: fp32->bf16 of x|Wq|Wk|Wv|Wo
// block 8192: mask compaction scan  -> cidx / vidx / maskc / meta
// blocks 8193..12288: zero-fill of out
// ---------------------------------------------------------------------------
__global__ void cvt_kernel(const float* __restrict__ x,
                           const float* __restrict__ wq,
                           const float* __restrict__ wk,
                           const float* __restrict__ wv,
                           const float* __restrict__ wo,
                           const int* __restrict__ maskp,
                           unsigned short* __restrict__ dst,
                           unsigned* __restrict__ cidx,
                           unsigned short* __restrict__ vidx,
                           unsigned short* __restrict__ maskc,
                           unsigned* __restrict__ meta,
                           float* __restrict__ outz) {
    if (blockIdx.x > 8192) {
        long long idx =
            ((long long)(blockIdx.x - 8193) * 256 + threadIdx.x) * 4;
        if (idx < 4194304LL) {
            float4 z = {0.f, 0.f, 0.f, 0.f};
            *(float4*)(outz + idx) = z;
        }
        return;
    }
    if (blockIdx.x == 8192) {
        __shared__ unsigned ps[256];
        int t = threadIdx.x;
        int base = t * 16;
        int bb = base >> 11;
        unsigned mv = 0, cnt = 0;
#pragma unroll
        for (int i = 0; i < 16; i++) {
            if (maskp[base + i]) { mv |= (1u << i); cnt++; }
        }
        ps[t] = cnt;
        __syncthreads();
        for (int off = 1; off < 128; off <<= 1) {
            unsigned add = ((t & 127) >= off) ? ps[t - off] : 0;
            __syncthreads();
            ps[t] += add;
            __syncthreads();
        }
        unsigned cnt0 = ps[127], cnt1 = ps[255];
        unsigned ex = ps[t] - cnt;   // within-batch exclusive prefix
        unsigned local = ex;
        unsigned g = (bb ? cnt0 : 0) + ex;
        for (int i = 0; i < 16; i++) {
            if (mv & (1u << i)) {
                cidx[g] = (unsigned)(base + i);
                vidx[bb * 2048 + local] =
                    (unsigned short)(base + i - bb * 2048);
                maskc[bb * 2048 + local] = 0x3F80;
                g++; local++;
            }
        }
        if (t == 0) { meta[0] = cnt0; meta[1] = cnt1; meta[2] = cnt0 + cnt1; }
        __syncthreads();
        unsigned C = cnt0 + cnt1;
        for (unsigned i = C + t; i < 4224; i += 256) cidx[i] = 0;
        for (unsigned i = cnt0 + t; i < 2048; i += 256) {
            vidx[i] = 0; maskc[i] = 0;
        }
        for (unsigned i = cnt1 + t; i < 2048; i += 256) {
            vidx[2048 + i] = 0; maskc[2048 + i] = 0;
        }
        return;
    }
    long long i0 = ((long long)blockIdx.x * blockDim.x + threadIdx.x) * 4;
    const float* src; long long off;
    if (i0 < 4194304LL)      { src = x;  off = i0; }
    else if (i0 < 5242880LL) { src = wq; off = i0 - 4194304LL; }
    else if (i0 < 6291456LL) { src = wk; off = i0 - 5242880LL; }
    else if (i0 < 7340032LL) { src = wv; off = i0 - 6291456LL; }
    else                     { src = wo; off = i0 - 7340032LL; }
    float4 f = *(const float4*)(src + off);
    ushort4 o;
    o.x = f2bf(f.x); o.y = f2bf(f.y); o.z = f2bf(f.z); o.w = f2bf(f.w);
    *(ushort4*)(dst + i0) = o;
}

// ---------------------------------------------------------------------------
// QKV projection GEMM over COMPACTED rows, 64x128 (MxN) tiles. m97 staging.
// ---------------------------------------------------------------------------
__global__ __launch_bounds__(256) void qkv_gemm(
    const unsigned short* __restrict__ A,
    const unsigned short* __restrict__ Bm,
    const float* __restrict__ bq, const float* __restrict__ bk,
    const float* __restrict__ bv,
    const unsigned* __restrict__ cidx, const unsigned* __restrict__ meta,
    unsigned short* __restrict__ qout, unsigned short* __restrict__ kout,
    unsigned short* __restrict__ vout) {
    const int K = 1024;
    int C  = (int)meta[2];
    int c0 = (int)meta[0];
    int m0 = blockIdx.y * 64, n0 = blockIdx.x * 128;
    if (m0 >= C) return;
    __shared__ __align__(16) unsigned short As[64 * 32];
    __shared__ __align__(16) unsigned short Bs[128 * 32];
    int t = threadIdx.x;
    int w = t >> 6, lane = t & 63;
    int wm = (w >> 1) * 32, wn = (w & 1) * 64;
    int c = lane & 15, qd = lane >> 4;

    f32x4 acc[2][4];
#pragma unroll
    for (int i = 0; i < 2; i++)
#pragma unroll
        for (int j = 0; j < 4; j++) acc[i][j] = zero4();

    int srow = t >> 2, sseg = (t & 3) * 8;
    int r1 = (int)cidx[m0 + srow];
    const unsigned short* ag1 = A + (long long)r1 * K + sseg;
    const unsigned short* bg1 = Bm + (long long)(n0 + srow) * K + sseg;
    const unsigned short* bg2 = bg1 + 64LL * K;
    unsigned short* la1 = As + t * 8;
    unsigned short* lb1 = Bs + t * 8;
    unsigned short* lb2 = Bs + (t + 256) * 8;

    for (int kk = 0; kk < K; kk += 32) {
        __syncthreads();
        ASYNC_COPY16(ag1 + kk, la1);
        ASYNC_COPY16(bg1 + kk, lb1);
        ASYNC_COPY16(bg2 + kk, lb2);
        __syncthreads();
        bf16x8 af[2], bf[4];
#pragma unroll
        for (int i = 0; i < 2; i++)
            af[i] = *(const bf16x8*)(As + (wm + i * 16 + c) * 32 + qd * 8);
#pragma unroll
        for (int j = 0; j < 4; j++)
            bf[j] = *(const bf16x8*)(Bs + (wn + j * 16 + c) * 32 + qd * 8);
#pragma unroll
        for (int i = 0; i < 2; i++)
#pragma unroll
            for (int j = 0; j < 4; j++)
                acc[i][j] = __builtin_amdgcn_mfma_f32_16x16x32_bf16(
                    af[i], bf[j], acc[i][j], 0, 0, 0);
    }

    int gr[2][4];
#pragma unroll
    for (int i = 0; i < 2; i++)
#pragma unroll
        for (int r = 0; r < 4; r++) {
            int m = m0 + wm + i * 16 + qd * 4 + r;
            gr[i][r] = (m < C) ? (int)cidx[m] : -1;
        }

    const float QSCALE = 0.125f * LOG2E;
#pragma unroll
    for (int i = 0; i < 2; i++) {
        int m_base = m0 + wm + i * 16 + qd * 4;
#pragma unroll
        for (int j = 0; j < 4; j++) {
            int n = n0 + wn + j * 16 + c;
            int sel = n >> 10, within = n & 1023;
            int head = within >> 6, d = within & 63;
            if (sel == 0) {
                float ba = bq[within];
#pragma unroll
                for (int r = 0; r < 4; r++) {
                    if (gr[i][r] >= 0) {
                        int bb = gr[i][r] >> 11;
                        int loc = (m_base + r) - (bb ? c0 : 0);
                        qout[(((long long)(bb * NH + head)) * T_ + loc) * HD +
                             d] = f2bf((acc[i][j][r] + ba) * QSCALE);
                    }
                }
            } else if (sel == 1) {
                float ba = bk[within];
#pragma unroll
                for (int r = 0; r < 4; r++) {
                    if (gr[i][r] >= 0) {
                        int bb = gr[i][r] >> 11;
                        int loc = (m_base + r) - (bb ? c0 : 0);
                        kout[(((long long)(bb * NH + head)) * T_ + loc) * HD +
                             d] = f2bf(acc[i][j][r] + ba);
                    }
                }
            } else {
                float ba = bv[within];
                int g0 = gr[i][0], g3 = gr[i][3];
                int bb0 = g0 >> 11;
                int loc0 = m_base - (bb0 ? c0 : 0);
                if (g3 >= 0 && bb0 == (g3 >> 11) && ((loc0 & 3) == 0)) {
                    uint2 ov;
                    ov.x = pkbf(acc[i][j][0] + ba, acc[i][j][1] + ba);
                    ov.y = pkbf(acc[i][j][2] + ba, acc[i][j][3] + ba);
                    *(uint2*)(vout +
                              (((long long)(bb0 * NH + head)) * HD + d) * T_ +
                              loc0) = ov;
                } else {
#pragma unroll
                    for (int r = 0; r < 4; r++) {
                        if (gr[i][r] >= 0) {
                            int bb = gr[i][r] >> 11;
                            int loc = (m_base + r) - (bb ? c0 : 0);
                            vout[(((long long)(bb * NH + head)) * HD + d) *
                                     T_ +
                                 loc] = f2bf(acc[i][j][r] + ba);
                        }
                    }
                }
            }
        }
    }
}

// ---------------------------------------------------------------------------
// Output projection GEMM over COMPACTED rows, 64x64 tiles.
// ---------------------------------------------------------------------------
__global__ __launch_bounds__(256) void out_gemm(
    const unsigned short* __restrict__ A,
    const unsigned short* __restrict__ Bm,
    const float* __restrict__ bo,
    const unsigned* __restrict__ cidx, const unsigned* __restrict__ meta,
    float* __restrict__ out) {
    const int K = 1024;
    int C = (int)meta[2];
    int m0 = blockIdx.y * 64, n0 = blockIdx.x * 64;
    if (m0 >= C) return;
    __shared__ __align__(16) unsigned short As[64 * 32];
    __shared__ __align__(16) unsigned short Bs[64 * 32];
    int t = threadIdx.x;
    int w = t >> 6, lane = t & 63;
    int wm = (w >> 1) * 32, wn = (w & 1) * 32;
    int c = lane & 15, qd = lane >> 4;

    f32x4 acc[2][2];
#pragma unroll
    for (int i = 0; i < 2; i++)
#pragma unroll
        for (int j = 0; j < 2; j++) acc[i][j] = zero4();

    int srow = t >> 2, sseg = (t & 3) * 8;
    int r1 = (int)cidx[m0 + srow];
    const unsigned short* ag1 = A + (long long)r1 * K + sseg;
    const unsigned short* bg1 = Bm + (long long)(n0 + srow) * K + sseg;
    unsigned short* la1 = As + t * 8;
    unsigned short* lb1 = Bs + t * 8;

    for (int kk = 0; kk < K; kk += 32) {
        __syncthreads();
        ASYNC_COPY16(ag1 + kk, la1);
        ASYNC_COPY16(bg1 + kk, lb1);
        __syncthreads();
        bf16x8 af[2], bf[2];
#pragma unroll
        for (int i = 0; i < 2; i++)
            af[i] = *(const bf16x8*)(As + (wm + i * 16 + c) * 32 + qd * 8);
#pragma unroll
        for (int j = 0; j < 2; j++)
            bf[j] = *(const bf16x8*)(Bs + (wn + j * 16 + c) * 32 + qd * 8);
#pragma unroll
        for (int i = 0; i < 2; i++)
#pragma unroll
            for (int j = 0; j < 2; j++)
                acc[i][j] = __builtin_amdgcn_mfma_f32_16x16x32_bf16(
                    af[i], bf[j], acc[i][j], 0, 0, 0);
    }

#pragma unroll
    for (int i = 0; i < 2; i++) {
#pragma unroll
        for (int r = 0; r < 4; r++) {
            int m = m0 + wm + i * 16 + qd * 4 + r;
            if (m < C) {
                long long g = (long long)cidx[m];
#pragma unroll
                for (int j = 0; j < 2; j++) {
                    int n = n0 + wn + j * 16 + c;
                    out[g * 1024 + n] = acc[i][j][r] + bo[n];
                }
            }
        }
    }
}

// ---------------------------------------------------------------------------
// Attention v8: 512-thread blocks, SPLIT-K over key tiles. Wave-group g
// (waves 0-3 / 4-7) processes key tiles kt = g, g+2, ... with its own
// double-buffered LDS region; fixed-max softmax means partials add — group 1
// dumps fp32 O/l into LDS (overlaying K buffers), group 0 combines and
// writes. Same total LDS traffic as v7, 2x resident waves/SIMD.
// ---------------------------------------------------------------------------
__global__ __launch_bounds__(512, 2) void attn_kernel(
    const unsigned short* __restrict__ qg,
    const unsigned short* __restrict__ kg,
    const unsigned short* __restrict__ vTg,
    const float* __restrict__ rel_bias,          // [9][16]
    const unsigned short* __restrict__ maskc,    // [B][2048] bf16 1/0
    const unsigned short* __restrict__ vidxg,    // [B][2048] u16 true t
    const unsigned* __restrict__ meta,
    unsigned short* __restrict__ hid) {          // [B*T][H] (true rows)
    int hb = blockIdx.x, qt = blockIdx.y;
    int h = hb & 15, b = hb >> 4;
    int cnt = (int)meta[b];
    if (qt * 128 >= cnt) return;
    int nkt = (cnt + 63) >> 6;
    int t = threadIdx.x;
    int g = t >> 8;            // key-split group (0/1)
    int tg = t & 255;          // thread-in-group
    int w = tg >> 6;           // wave-in-group 0..3
    int lane = t & 63;
    int c = lane & 15, qd = lane >> 4;

    __shared__ __align__(16) unsigned short lk[2][2][64 * 72];   // [g][buf]
    __shared__ __align__(16) unsigned short lvT[2][2][64 * 72];
    __shared__ __align__(16) unsigned short lmk[2][2][64];
    __shared__ __align__(16) unsigned short lki[2][2][64];
    __shared__ float lrbf[16];

    if (t < 9) lrbf[t] = rel_bias[t * 16 + h] * LOG2E;
    float rb0 = rel_bias[0 * 16 + h] * LOG2E;
    float rb8 = rel_bias[8 * 16 + h] * LOG2E;

    const unsigned short* qp =
        qg + (((long long)(b * NH + h)) * T_ + qt * 128) * HD;
    const unsigned short* kp = kg + ((long long)(b * NH + h)) * T_ * HD;
    const unsigned short* vp = vTg + ((long long)(b * NH + h)) * HD * T_;

    bf16x8 qf[2][2];
#pragma unroll
    for (int mt = 0; mt < 2; mt++)
#pragma unroll
        for (int ks = 0; ks < 2; ks++)
            qf[mt][ks] = *(const bf16x8*)(qp + (w * 32 + mt * 16 + c) * HD +
                                          ks * 32 + qd * 8);

    const int imin = qt * 128 + w * 32;
    int imin_t = (int)vidxg[b * 2048 + min(imin, cnt - 1)];
    int imax_t = (int)vidxg[b * 2048 + min(imin + 31, cnt - 1)];
    int itrue[2];
#pragma unroll
    for (int mt = 0; mt < 2; mt++)
        itrue[mt] =
            (int)vidxg[b * 2048 + min(imin + mt * 16 + c, cnt - 1)];

    f32x4 o[4][2];
    f32x4 lacc[2];
#pragma unroll
    for (int dt = 0; dt < 4; dt++)
#pragma unroll
        for (int mt = 0; mt < 2; mt++) o[dt][mt] = zero4();
    lacc[0] = zero4(); lacc[1] = zero4();

    int srow = tg >> 2, sseg = (tg & 3) * 16;
    const unsigned short* kst = kp + srow * HD + sseg;
    const unsigned short* vst = vp + srow * T_ + sseg;
    const unsigned short* mst = maskc + b * 2048 + tg;
    const unsigned short* ist = vidxg + b * 2048 + tg * 8;

    int kt0 = min(g, nkt - 1);
    uint4 rk0 = *(const uint4*)(kst + kt0 * 64 * HD);
    uint4 rk1 = *(const uint4*)(kst + kt0 * 64 * HD + 8);
    uint4 rv0 = *(const uint4*)(vst + kt0 * 64);
    uint4 rv1 = *(const uint4*)(vst + kt0 * 64 + 8);
    unsigned short rm = (tg < 64) ? mst[kt0 * 64] : 0;
    uint4 rki = {0, 0, 0, 0};
    if (tg < 8) rki = *(const uint4*)(ist + kt0 * 64);

    int maxiter = (nkt + 1) >> 1;
    for (int it = 0; it < maxiter; it++) {
        int kta = g + 2 * it;
        bool active = (kta < nkt);
        unsigned short* KB = lk[g][it & 1];
        unsigned short* VB = lvT[g][it & 1];
        unsigned short* MK = lmk[g][it & 1];
        unsigned short* KI = lki[g][it & 1];
        *(uint4*)(KB + srow * 72 + sseg)     = rk0;
        *(uint4*)(KB + srow * 72 + sseg + 8) = rk1;
        *(uint4*)(VB + srow * 72 + sseg)     = rv0;
        *(uint4*)(VB + srow * 72 + sseg + 8) = rv1;
        if (tg < 64) MK[tg] = rm;
        if (tg < 8) *(uint4*)(KI + tg * 8) = rki;
        {
            int ktn = min(kta + 2, nkt - 1);
            rk0 = *(const uint4*)(kst + ktn * 64 * HD);
            rk1 = *(const uint4*)(kst + ktn * 64 * HD + 8);
            rv0 = *(const uint4*)(vst + ktn * 64);
            rv1 = *(const uint4*)(vst + ktn * 64 + 8);
            if (tg < 64) rm = mst[ktn * 64];
            if (tg < 8) rki = *(const uint4*)(ist + ktn * 64);
        }
        __syncthreads();
        if (!active) continue;

        int j0 = kta * 64;
        int jlo_t = (int)KI[0];
        int jhi_t = (int)KI[min(63, cnt - 1 - j0)];
        bool far_lo = (jhi_t <= imin_t - 4);
        bool far_hi = (jlo_t >= imax_t + 4);
        float ub = far_lo ? rb0 : rb8;
        bool nearband = !(far_lo || far_hi);

#pragma unroll
        for (int jt = 0; jt < 4; jt++) {
            bf16x8 kf0 = *(const bf16x8*)(KB + (jt * 16 + c) * 72 + qd * 8);
            bf16x8 kf1 =
                *(const bf16x8*)(KB + (jt * 16 + c) * 72 + 32 + qd * 8);
            bf16x4 vld4 = *(const bf16x4*)(MK + jt * 16 + qd * 4);
            ushort4 kiv = *(const ushort4*)(KI + jt * 16 + qd * 4);
            bf16x4 vf[4];
#pragma unroll
            for (int dt = 0; dt < 4; dt++)
                vf[dt] = *(const bf16x4*)(VB + (dt * 16 + c) * 72 + jt * 16 +
                                          qd * 4);
#pragma unroll
            for (int mt = 0; mt < 2; mt++) {
                f32x4 acc = zero4();
                acc = __builtin_amdgcn_mfma_f32_16x16x32_bf16(kf0, qf[mt][0],
                                                              acc, 0, 0, 0);
                acc = __builtin_amdgcn_mfma_f32_16x16x32_bf16(kf1, qf[mt][1],
                                                              acc, 0, 0, 0);
                float p0, p1, p2, p3;
                if (nearband) {
                    int itq = itrue[mt];
                    int r0 = (int)kiv.x - itq;
                    r0 = r0 < -4 ? -4 : (r0 > 4 ? 4 : r0);
                    int r1 = (int)kiv.y - itq;
                    r1 = r1 < -4 ? -4 : (r1 > 4 ? 4 : r1);
                    int r2 = (int)kiv.z - itq;
                    r2 = r2 < -4 ? -4 : (r2 > 4 ? 4 : r2);
                    int r3 = (int)kiv.w - itq;
                    r3 = r3 < -4 ? -4 : (r3 > 4 ? 4 : r3);
                    p0 = EXP2(acc[0] + lrbf[r0 + 4]);
                    p1 = EXP2(acc[1] + lrbf[r1 + 4]);
                    p2 = EXP2(acc[2] + lrbf[r2 + 4]);
                    p3 = EXP2(acc[3] + lrbf[r3 + 4]);
                } else {
                    p0 = EXP2(acc[0] + ub);
                    p1 = EXP2(acc[1] + ub);
                    p2 = EXP2(acc[2] + ub);
                    p3 = EXP2(acc[3] + ub);
                }
                bf16x4 pfrag = mk4(pkbf(p0, p1), pkbf(p2, p3));
                lacc[mt] = __builtin_amdgcn_mfma_f32_16x16x16bf16_1k(
                    vld4, pfrag, lacc[mt], 0, 0, 0);
#pragma unroll
                for (int dt = 0; dt < 4; dt++)
                    o[dt][mt] = __builtin_amdgcn_mfma_f32_16x16x16bf16_1k(
                        vf[dt], pfrag, o[dt][mt], 0, 0, 0);
            }
        }
    }

    // combine: group 1 -> LDS (overlay lk), group 0 adds + writes
    __syncthreads();
    float* cb = (float*)(&lk[0][0][0]);   // 256 lanes x 34 f32 = 34,816 B
    int li = w * 64 + lane;
    if (g == 1) {
#pragma unroll
        for (int dt = 0; dt < 4; dt++)
#pragma unroll
            for (int mt = 0; mt < 2; mt++)
#pragma unroll
                for (int r = 0; r < 4; r++)
                    cb[li * 34 + dt * 8 + mt * 4 + r] = o[dt][mt][r];
        cb[li * 34 + 32] = lacc[0][0];
        cb[li * 34 + 33] = lacc[1][0];
    }
    __syncthreads();
    if (g == 0) {
#pragma unroll
        for (int mt = 0; mt < 2; mt++) {
            int rc = imin + mt * 16 + c;
            if (rc < cnt) {
                float lt = lacc[mt][0] + cb[li * 34 + 32 + mt];
                float invl = 1.0f / lt;
                long long row = (long long)b * T_ + itrue[mt];
#pragma unroll
                for (int dt = 0; dt < 4; dt++) {
                    float o0 = o[dt][mt][0] + cb[li * 34 + dt * 8 + mt * 4];
                    float o1 =
                        o[dt][mt][1] + cb[li * 34 + dt * 8 + mt * 4 + 1];
                    float o2 =
                        o[dt][mt][2] + cb[li * 34 + dt * 8 + mt * 4 + 2];
                    float o3 =
                        o[dt][mt][3] + cb[li * 34 + dt * 8 + mt * 4 + 3];
                    uint2 ov;
                    ov.x = pkbf(o0 * invl, o1 * invl);
                    ov.y = pkbf(o2 * invl, o3 * invl);
                    *(uint2*)(hid + row * H_ + h * HD + dt * 16 + qd * 4) =
                        ov;
                }
            }
        }
    }
}

extern "C" void kernel_launch(void* const* d_in, const int* in_sizes, int n_in,
                              void* d_out, int out_size, void* d_ws,
                              size_t ws_size, hipStream_t stream) {
    const float* x    = (const float*)d_in[0];
    const int* maskp  = (const int*)d_in[1];
    const float* Wq   = (const float*)d_in[2];
    const float* bq   = (const float*)d_in[3];
    const float* Wk   = (const float*)d_in[4];
    const float* bk   = (const float*)d_in[5];
    const float* Wv   = (const float*)d_in[6];
    const float* bv   = (const float*)d_in[7];
    const float* Wo   = (const float*)d_in[8];
    const float* bo   = (const float*)d_in[9];
    const float* rb   = (const float*)d_in[10];
    float* out        = (float*)d_out;

    unsigned short* ws = (unsigned short*)d_ws;
    unsigned short* xb    = ws;                 // [0, 4M) elems
    unsigned short* wqkv  = ws + 4194304LL;     // [4M, 7M)
    unsigned short* wo_b  = ws + 7340032LL;     // [7M, 8M)
    unsigned short* qb    = ws + 8388608LL;     // [b,h,local,d]
    unsigned short* kb    = ws + 12582912LL;    // [b,h,local,d]
    unsigned short* vTb   = ws + 16777216LL;    // [b,h,d,local]
    unsigned short* hid   = ws + 20971520LL;    // [b*t][h*64+d] true rows
    unsigned* meta        = (unsigned*)(ws + 25165824LL);       // 4 u32
    unsigned* cidx        = (unsigned*)(ws + 25165856LL);       // 4224 u32
    unsigned short* vidx  = ws + 25174304LL;    // 4096 u16
    unsigned short* maskc = ws + 25178400LL;    // 4096 bf16

    cvt_kernel<<<12289, 256, 0, stream>>>(x, Wq, Wk, Wv, Wo, maskp, ws, cidx,
                                          vidx, maskc, meta, out);
    qkv_gemm<<<dim3(24, 64), 256, 0, stream>>>(xb, wqkv, bq, bk, bv, cidx,
                                               meta, qb, kb, vTb);
    attn_kernel<<<dim3(32, 16), 512, 0, stream>>>(qb, kb, vTb, rb, maskc,
                                                  vidx, meta, hid);
    out_gemm<<<dim3(16, 64), 256, 0, stream>>>(hid, wo_b, bo, cidx, meta,
                                               out);
}

// Round 11
// 182.053 us; speedup vs baseline: 1.0161x; 1.0161x over previous
//
#include <hip/hip_runtime.h>
#include <hip/hip_bf16.h>

#define B_ 2
#define T_ 2048
#define H_ 1024
#define NH 16
#define HD 64

typedef __attribute__((ext_vector_type(8))) short bf16x8;
typedef __attribute__((ext_vector_type(4))) short bf16x4;
typedef __attribute__((ext_vector_type(4))) float f32x4;

#define ASYNC_COPY16(gptr, lptr)                                              \
    __builtin_amdgcn_global_load_lds(                                         \
        (const __attribute__((address_space(1))) void*)(gptr),                \
        (__attribute__((address_space(3))) void*)(lptr), 16, 0, 0)

#if __has_builtin(__builtin_amdgcn_exp2f)
#define EXP2(x) __builtin_amdgcn_exp2f(x)
#else
static __device__ inline float EXP2(float x) {
    float r;
    asm volatile("v_exp_f32 %0, %1" : "=v"(r) : "v"(x));
    return r;
}
#endif

static __device__ inline unsigned short f2bf(float f) {
    union { float f; unsigned u; } v; v.f = f;
    unsigned r = v.u + 0x7fff + ((v.u >> 16) & 1);
    return (unsigned short)(r >> 16);
}

static __device__ inline unsigned pkbf(float a, float b) {
    float2 t2; t2.x = a; t2.y = b;
    __hip_bfloat162 h = __float22bfloat162_rn(t2);
    union { __hip_bfloat162 h; unsigned u; } cv; cv.h = h;
    return cv.u;
}

static __device__ inline bf16x4 mk4(unsigned lo, unsigned hi) {
    union { bf16x4 v; unsigned u[2]; } cv;
    cv.u[0] = lo; cv.u[1] = hi;
    return cv.v;
}

static __device__ inline f32x4 zero4() {
    f32x4 z = {0.f, 0.f, 0.f, 0.f};
    return z;
}

#define LOG2E 1.44269504088896f

// ---------------------------------------------------------------------------
// blocks 0..8191: fp32->bf16 of x|Wq|Wk|Wv|Wo
// block 8192: mask compaction scan  -> cidx / vidx / maskc / meta
// blocks 8193..12288: zero-fill of out
// ---------------------------------------------------------------------------
__global__ void cvt_kernel(const float* __restrict__ x,
                           const float* __restrict__ wq,
                           const float* __restrict__ wk,
                           const float* __restrict__ wv,
                           const float* __restrict__ wo,
                           const int* __restrict__ maskp,
                           unsigned short* __restrict__ dst,
                           unsigned* __restrict__ cidx,
                           unsigned short* __restrict__ vidx,
                           unsigned short* __restrict__ maskc,
                           unsigned* __restrict__ meta,
                           float* __restrict__ outz) {
    if (blockIdx.x > 8192) {
        long long idx =
            ((long long)(blockIdx.x - 8193) * 256 + threadIdx.x) * 4;
        if (idx < 4194304LL) {
            float4 z = {0.f, 0.f, 0.f, 0.f};
            *(float4*)(outz + idx) = z;
        }
        return;
    }
    if (blockIdx.x == 8192) {
        __shared__ unsigned ps[256];
        int t = threadIdx.x;
        int base = t * 16;
        int bb = base >> 11;
        unsigned mv = 0, cnt = 0;
#pragma unroll
        for (int i = 0; i < 16; i++) {
            if (maskp[base + i]) { mv |= (1u << i); cnt++; }
        }
        ps[t] = cnt;
        __syncthreads();
        for (int off = 1; off < 128; off <<= 1) {
            unsigned add = ((t & 127) >= off) ? ps[t - off] : 0;
            __syncthreads();
            ps[t] += add;
            __syncthreads();
        }
        unsigned cnt0 = ps[127], cnt1 = ps[255];
        unsigned ex = ps[t] - cnt;   // within-batch exclusive prefix
        unsigned local = ex;
        unsigned g = (bb ? cnt0 : 0) + ex;
        for (int i = 0; i < 16; i++) {
            if (mv & (1u << i)) {
                cidx[g] = (unsigned)(base + i);
                vidx[bb * 2048 + local] =
                    (unsigned short)(base + i - bb * 2048);
                maskc[bb * 2048 + local] = 0x3F80;
                g++; local++;
            }
        }
        if (t == 0) { meta[0] = cnt0; meta[1] = cnt1; meta[2] = cnt0 + cnt1; }
        __syncthreads();
        unsigned C = cnt0 + cnt1;
        for (unsigned i = C + t; i < 4224; i += 256) cidx[i] = 0;
        for (unsigned i = cnt0 + t; i < 2048; i += 256) {
            vidx[i] = 0; maskc[i] = 0;
        }
        for (unsigned i = cnt1 + t; i < 2048; i += 256) {
            vidx[2048 + i] = 0; maskc[2048 + i] = 0;
        }
        return;
    }
    long long i0 = ((long long)blockIdx.x * blockDim.x + threadIdx.x) * 4;
    const float* src; long long off;
    if (i0 < 4194304LL)      { src = x;  off = i0; }
    else if (i0 < 5242880LL) { src = wq; off = i0 - 4194304LL; }
    else if (i0 < 6291456LL) { src = wk; off = i0 - 5242880LL; }
    else if (i0 < 7340032LL) { src = wv; off = i0 - 6291456LL; }
    else                     { src = wo; off = i0 - 7340032LL; }
    float4 f = *(const float4*)(src + off);
    ushort4 o;
    o.x = f2bf(f.x); o.y = f2bf(f.y); o.z = f2bf(f.z); o.w = f2bf(f.w);
    *(ushort4*)(dst + i0) = o;
}

// ---------------------------------------------------------------------------
// QKV projection GEMM over COMPACTED rows, 64x128 (MxN) tiles. m97 staging.
// ---------------------------------------------------------------------------
__global__ __launch_bounds__(256) void qkv_gemm(
    const unsigned short* __restrict__ A,
    const unsigned short* __restrict__ Bm,
    const float* __restrict__ bq, const float* __restrict__ bk,
    const float* __restrict__ bv,
    const unsigned* __restrict__ cidx, const unsigned* __restrict__ meta,
    unsigned short* __restrict__ qout, unsigned short* __restrict__ kout,
    unsigned short* __restrict__ vout) {
    const int K = 1024;
    int C  = (int)meta[2];
    int c0 = (int)meta[0];
    int m0 = blockIdx.y * 64, n0 = blockIdx.x * 128;
    if (m0 >= C) return;
    __shared__ __align__(16) unsigned short As[64 * 32];
    __shared__ __align__(16) unsigned short Bs[128 * 32];
    int t = threadIdx.x;
    int w = t >> 6, lane = t & 63;
    int wm = (w >> 1) * 32, wn = (w & 1) * 64;
    int c = lane & 15, qd = lane >> 4;

    f32x4 acc[2][4];
#pragma unroll
    for (int i = 0; i < 2; i++)
#pragma unroll
        for (int j = 0; j < 4; j++) acc[i][j] = zero4();

    int srow = t >> 2, sseg = (t & 3) * 8;
    int r1 = (int)cidx[m0 + srow];
    const unsigned short* ag1 = A + (long long)r1 * K + sseg;
    const unsigned short* bg1 = Bm + (long long)(n0 + srow) * K + sseg;
    const unsigned short* bg2 = bg1 + 64LL * K;
    unsigned short* la1 = As + t * 8;
    unsigned short* lb1 = Bs + t * 8;
    unsigned short* lb2 = Bs + (t + 256) * 8;

    for (int kk = 0; kk < K; kk += 32) {
        __syncthreads();
        ASYNC_COPY16(ag1 + kk, la1);
        ASYNC_COPY16(bg1 + kk, lb1);
        ASYNC_COPY16(bg2 + kk, lb2);
        __syncthreads();
        bf16x8 af[2], bf[4];
#pragma unroll
        for (int i = 0; i < 2; i++)
            af[i] = *(const bf16x8*)(As + (wm + i * 16 + c) * 32 + qd * 8);
#pragma unroll
        for (int j = 0; j < 4; j++)
            bf[j] = *(const bf16x8*)(Bs + (wn + j * 16 + c) * 32 + qd * 8);
#pragma unroll
        for (int i = 0; i < 2; i++)
#pragma unroll
            for (int j = 0; j < 4; j++)
                acc[i][j] = __builtin_amdgcn_mfma_f32_16x16x32_bf16(
                    af[i], bf[j], acc[i][j], 0, 0, 0);
    }

    int gr[2][4];
#pragma unroll
    for (int i = 0; i < 2; i++)
#pragma unroll
        for (int r = 0; r < 4; r++) {
            int m = m0 + wm + i * 16 + qd * 4 + r;
            gr[i][r] = (m < C) ? (int)cidx[m] : -1;
        }

    const float QSCALE = 0.125f * LOG2E;
#pragma unroll
    for (int i = 0; i < 2; i++) {
        int m_base = m0 + wm + i * 16 + qd * 4;
#pragma unroll
        for (int j = 0; j < 4; j++) {
            int n = n0 + wn + j * 16 + c;
            int sel = n >> 10, within = n & 1023;
            int head = within >> 6, d = within & 63;
            if (sel == 0) {
                float ba = bq[within];
#pragma unroll
                for (int r = 0; r < 4; r++) {
                    if (gr[i][r] >= 0) {
                        int bb = gr[i][r] >> 11;
                        int loc = (m_base + r) - (bb ? c0 : 0);
                        qout[(((long long)(bb * NH + head)) * T_ + loc) * HD +
                             d] = f2bf((acc[i][j][r] + ba) * QSCALE);
                    }
                }
            } else if (sel == 1) {
                float ba = bk[within];
#pragma unroll
                for (int r = 0; r < 4; r++) {
                    if (gr[i][r] >= 0) {
                        int bb = gr[i][r] >> 11;
                        int loc = (m_base + r) - (bb ? c0 : 0);
                        kout[(((long long)(bb * NH + head)) * T_ + loc) * HD +
                             d] = f2bf(acc[i][j][r] + ba);
                    }
                }
            } else {
                float ba = bv[within];
                int g0 = gr[i][0], g3 = gr[i][3];
                int bb0 = g0 >> 11;
                int loc0 = m_base - (bb0 ? c0 : 0);
                if (g3 >= 0 && bb0 == (g3 >> 11) && ((loc0 & 3) == 0)) {
                    uint2 ov;
                    ov.x = pkbf(acc[i][j][0] + ba, acc[i][j][1] + ba);
                    ov.y = pkbf(acc[i][j][2] + ba, acc[i][j][3] + ba);
                    *(uint2*)(vout +
                              (((long long)(bb0 * NH + head)) * HD + d) * T_ +
                              loc0) = ov;
                } else {
#pragma unroll
                    for (int r = 0; r < 4; r++) {
                        if (gr[i][r] >= 0) {
                            int bb = gr[i][r] >> 11;
                            int loc = (m_base + r) - (bb ? c0 : 0);
                            vout[(((long long)(bb * NH + head)) * HD + d) *
                                     T_ +
                                 loc] = f2bf(acc[i][j][r] + ba);
                        }
                    }
                }
            }
        }
    }
}

// ---------------------------------------------------------------------------
// Output projection GEMM over COMPACTED rows, 64x64 tiles.
// ---------------------------------------------------------------------------
__global__ __launch_bounds__(256) void out_gemm(
    const unsigned short* __restrict__ A,
    const unsigned short* __restrict__ Bm,
    const float* __restrict__ bo,
    const unsigned* __restrict__ cidx, const unsigned* __restrict__ meta,
    float* __restrict__ out) {
    const int K = 1024;
    int C = (int)meta[2];
    int m0 = blockIdx.y * 64, n0 = blockIdx.x * 64;
    if (m0 >= C) return;
    __shared__ __align__(16) unsigned short As[64 * 32];
    __shared__ __align__(16) unsigned short Bs[64 * 32];
    int t = threadIdx.x;
    int w = t >> 6, lane = t & 63;
    int wm = (w >> 1) * 32, wn = (w & 1) * 32;
    int c = lane & 15, qd = lane >> 4;

    f32x4 acc[2][2];
#pragma unroll
    for (int i = 0; i < 2; i++)
#pragma unroll
        for (int j = 0; j < 2; j++) acc[i][j] = zero4();

    int srow = t >> 2, sseg = (t & 3) * 8;
    int r1 = (int)cidx[m0 + srow];
    const unsigned short* ag1 = A + (long long)r1 * K + sseg;
    const unsigned short* bg1 = Bm + (long long)(n0 + srow) * K + sseg;
    unsigned short* la1 = As + t * 8;
    unsigned short* lb1 = Bs + t * 8;

    for (int kk = 0; kk < K; kk += 32) {
        __syncthreads();
        ASYNC_COPY16(ag1 + kk, la1);
        ASYNC_COPY16(bg1 + kk, lb1);
        __syncthreads();
        bf16x8 af[2], bf[2];
#pragma unroll
        for (int i = 0; i < 2; i++)
            af[i] = *(const bf16x8*)(As + (wm + i * 16 + c) * 32 + qd * 8);
#pragma unroll
        for (int j = 0; j < 2; j++)
            bf[j] = *(const bf16x8*)(Bs + (wn + j * 16 + c) * 32 + qd * 8);
#pragma unroll
        for (int i = 0; i < 2; i++)
#pragma unroll
            for (int j = 0; j < 2; j++)
                acc[i][j] = __builtin_amdgcn_mfma_f32_16x16x32_bf16(
                    af[i], bf[j], acc[i][j], 0, 0, 0);
    }

#pragma unroll
    for (int i = 0; i < 2; i++) {
#pragma unroll
        for (int r = 0; r < 4; r++) {
            int m = m0 + wm + i * 16 + qd * 4 + r;
            if (m < C) {
                long long g = (long long)cidx[m];
#pragma unroll
                for (int j = 0; j < 2; j++) {
                    int n = n0 + wn + j * 16 + c;
                    out[g * 1024 + n] = acc[i][j][r] + bo[n];
                }
            }
        }
    }
}

// ---------------------------------------------------------------------------
// Attention v9: v7 core with keys split across INDEPENDENT blocks (z=0/1,
// contiguous halves of the key tiles). Fixed-max softmax => partials add.
// fp32 O partials [z][bh][row][d] + l [z][bh][row]; combine_kernel merges.
// ---------------------------------------------------------------------------
__global__ __launch_bounds__(256, 2) void attn_kernel(
    const unsigned short* __restrict__ qg,
    const unsigned short* __restrict__ kg,
    const unsigned short* __restrict__ vTg,
    const float* __restrict__ rel_bias,          // [9][16]
    const unsigned short* __restrict__ maskc,    // [B][2048] bf16 1/0
    const unsigned short* __restrict__ vidxg,    // [B][2048] u16 true t
    const unsigned* __restrict__ meta,
    float* __restrict__ pO,                      // [2][32][2048][64] fp32
    float* __restrict__ pl) {                    // [2][32][2048] fp32
    int hb = blockIdx.x, qt = blockIdx.y, z = blockIdx.z;
    int h = hb & 15, b = hb >> 4;
    int cnt = (int)meta[b];
    if (qt * 128 >= cnt) return;
    int nkt = (cnt + 63) >> 6;
    int nh2 = (nkt + 1) >> 1;
    int ktbase = z ? nh2 : 0;
    int myn = z ? (nkt - nh2) : nh2;
    int t = threadIdx.x, w = t >> 6, lane = t & 63;
    int c = lane & 15, qd = lane >> 4;

    __shared__ __align__(16) unsigned short lk[2][64 * 72];   // K  [j][d]
    __shared__ __align__(16) unsigned short lvT[2][64 * 72];  // V^T[d][j]
    __shared__ __align__(16) unsigned short lmk[2][64];       // key valid bf16
    __shared__ __align__(16) unsigned short lki[2][64];       // key true pos
    __shared__ float lrbf[16];

    if (t < 9) lrbf[t] = rel_bias[t * 16 + h] * LOG2E;
    float rb0 = rel_bias[0 * 16 + h] * LOG2E;
    float rb8 = rel_bias[8 * 16 + h] * LOG2E;

    const unsigned short* qp =
        qg + (((long long)(b * NH + h)) * T_ + qt * 128) * HD;
    const unsigned short* kp = kg + ((long long)(b * NH + h)) * T_ * HD;
    const unsigned short* vp = vTg + ((long long)(b * NH + h)) * HD * T_;

    bf16x8 qf[2][2];
#pragma unroll
    for (int mt = 0; mt < 2; mt++)
#pragma unroll
        for (int ks = 0; ks < 2; ks++)
            qf[mt][ks] = *(const bf16x8*)(qp + (w * 32 + mt * 16 + c) * HD +
                                          ks * 32 + qd * 8);

    const int imin = qt * 128 + w * 32;
    int imin_t = (int)vidxg[b * 2048 + min(imin, cnt - 1)];
    int imax_t = (int)vidxg[b * 2048 + min(imin + 31, cnt - 1)];
    int itrue[2];
#pragma unroll
    for (int mt = 0; mt < 2; mt++)
        itrue[mt] =
            (int)vidxg[b * 2048 + min(imin + mt * 16 + c, cnt - 1)];

    f32x4 o[4][2];
    f32x4 lacc[2];
#pragma unroll
    for (int dt = 0; dt < 4; dt++)
#pragma unroll
        for (int mt = 0; mt < 2; mt++) o[dt][mt] = zero4();
    lacc[0] = zero4(); lacc[1] = zero4();

    int srow = t >> 2, sseg = (t & 3) * 16;
    const unsigned short* kst = kp + srow * HD + sseg;
    const unsigned short* vst = vp + srow * T_ + sseg;
    const unsigned short* mst = maskc + b * 2048 + t;
    const unsigned short* ist = vidxg + b * 2048 + t * 8;

    int kt0 = min(ktbase, nkt - 1);
    uint4 rk0 = *(const uint4*)(kst + kt0 * 64 * HD);
    uint4 rk1 = *(const uint4*)(kst + kt0 * 64 * HD + 8);
    uint4 rv0 = *(const uint4*)(vst + kt0 * 64);
    uint4 rv1 = *(const uint4*)(vst + kt0 * 64 + 8);
    unsigned short rm = (t < 64) ? mst[kt0 * 64] : 0;
    uint4 rki = {0, 0, 0, 0};
    if (t < 8) rki = *(const uint4*)(ist + kt0 * 64);

    for (int it = 0; it < myn; it++) {
        int kta = ktbase + it;
        unsigned short* KB = lk[it & 1];
        unsigned short* VB = lvT[it & 1];
        unsigned short* MK = lmk[it & 1];
        unsigned short* KI = lki[it & 1];
        *(uint4*)(KB + srow * 72 + sseg)     = rk0;
        *(uint4*)(KB + srow * 72 + sseg + 8) = rk1;
        *(uint4*)(VB + srow * 72 + sseg)     = rv0;
        *(uint4*)(VB + srow * 72 + sseg + 8) = rv1;
        if (t < 64) MK[t] = rm;
        if (t < 8) *(uint4*)(KI + t * 8) = rki;
        {
            int ktn = min(kta + 1, ktbase + myn - 1);
            rk0 = *(const uint4*)(kst + ktn * 64 * HD);
            rk1 = *(const uint4*)(kst + ktn * 64 * HD + 8);
            rv0 = *(const uint4*)(vst + ktn * 64);
            rv1 = *(const uint4*)(vst + ktn * 64 + 8);
            if (t < 64) rm = mst[ktn * 64];
            if (t < 8) rki = *(const uint4*)(ist + ktn * 64);
        }
        __syncthreads();

        int j0 = kta * 64;
        int jlo_t = (int)KI[0];
        int jhi_t = (int)KI[min(63, cnt - 1 - j0)];
        bool far_lo = (jhi_t <= imin_t - 4);
        bool far_hi = (jlo_t >= imax_t + 4);
        float ub = far_lo ? rb0 : rb8;
        bool nearband = !(far_lo || far_hi);

#pragma unroll
        for (int jt = 0; jt < 4; jt++) {
            bf16x8 kf0 = *(const bf16x8*)(KB + (jt * 16 + c) * 72 + qd * 8);
            bf16x8 kf1 =
                *(const bf16x8*)(KB + (jt * 16 + c) * 72 + 32 + qd * 8);
            bf16x4 vld4 = *(const bf16x4*)(MK + jt * 16 + qd * 4);
            ushort4 kiv = *(const ushort4*)(KI + jt * 16 + qd * 4);
            bf16x4 vf[4];
#pragma unroll
            for (int dt = 0; dt < 4; dt++)
                vf[dt] = *(const bf16x4*)(VB + (dt * 16 + c) * 72 + jt * 16 +
                                          qd * 4);
#pragma unroll
            for (int mt = 0; mt < 2; mt++) {
                f32x4 acc = zero4();
                acc = __builtin_amdgcn_mfma_f32_16x16x32_bf16(kf0, qf[mt][0],
                                                              acc, 0, 0, 0);
                acc = __builtin_amdgcn_mfma_f32_16x16x32_bf16(kf1, qf[mt][1],
                                                              acc, 0, 0, 0);
                float p0, p1, p2, p3;
                if (nearband) {
                    int itq = itrue[mt];
                    int r0 = (int)kiv.x - itq;
                    r0 = r0 < -4 ? -4 : (r0 > 4 ? 4 : r0);
                    int r1 = (int)kiv.y - itq;
                    r1 = r1 < -4 ? -4 : (r1 > 4 ? 4 : r1);
                    int r2 = (int)kiv.z - itq;
                    r2 = r2 < -4 ? -4 : (r2 > 4 ? 4 : r2);
                    int r3 = (int)kiv.w - itq;
                    r3 = r3 < -4 ? -4 : (r3 > 4 ? 4 : r3);
                    p0 = EXP2(acc[0] + lrbf[r0 + 4]);
                    p1 = EXP2(acc[1] + lrbf[r1 + 4]);
                    p2 = EXP2(acc[2] + lrbf[r2 + 4]);
                    p3 = EXP2(acc[3] + lrbf[r3 + 4]);
                } else {
                    p0 = EXP2(acc[0] + ub);
                    p1 = EXP2(acc[1] + ub);
                    p2 = EXP2(acc[2] + ub);
                    p3 = EXP2(acc[3] + ub);
                }
                bf16x4 pfrag = mk4(pkbf(p0, p1), pkbf(p2, p3));
                lacc[mt] = __builtin_amdgcn_mfma_f32_16x16x16bf16_1k(
                    vld4, pfrag, lacc[mt], 0, 0, 0);
#pragma unroll
                for (int dt = 0; dt < 4; dt++)
                    o[dt][mt] = __builtin_amdgcn_mfma_f32_16x16x16bf16_1k(
                        vf[dt], pfrag, o[dt][mt], 0, 0, 0);
            }
        }
    }

    // partial store: fp32 O [row][d] (f32x4, 64B-coalesced per qd quartet)
    float* po = pO + ((long long)(z * 32 + hb)) * 2048 * 64;
    float* plz = pl + ((long long)(z * 32 + hb)) * 2048;
#pragma unroll
    for (int mt = 0; mt < 2; mt++) {
        int row = imin + mt * 16 + c;
#pragma unroll
        for (int dt = 0; dt < 4; dt++)
            *(f32x4*)(po + (long long)row * 64 + dt * 16 + qd * 4) =
                o[dt][mt];
        if (qd == 0) plz[row] = lacc[mt][0];
    }
}

// ---------------------------------------------------------------------------
// Combine: hid[true_row] = (O0+O1)/(l0+l1) in bf16. Thread = (row, 32-d).
// ---------------------------------------------------------------------------
__global__ __launch_bounds__(256) void combine_kernel(
    const float* __restrict__ pO, const float* __restrict__ pl,
    const unsigned short* __restrict__ vidxg,
    const unsigned* __restrict__ meta,
    unsigned short* __restrict__ hid) {
    int hb = blockIdx.x, rb = blockIdx.y;
    int b = hb >> 4, h = hb & 15;
    int cnt = (int)meta[b];
    int t = threadIdx.x;
    int row = rb * 128 + (t >> 1);
    if (row >= cnt) return;
    int dh = (t & 1) * 32;
    long long base = (((long long)hb) * 2048 + row) * 64 + dh;
    const float* p0 = pO + base;
    const float* p1 = pO + 4194304LL + base;   // z stride = 32*2048*64
    float l = pl[hb * 2048 + row] + pl[65536 + hb * 2048 + row];
    float invl = 1.0f / l;
    int trow = (int)vidxg[b * 2048 + row];
    unsigned short* hp =
        hid + ((long long)b * T_ + trow) * H_ + h * 64 + dh;
    unsigned pk[16];
#pragma unroll
    for (int i = 0; i < 8; i++) {
        float4 a = *(const float4*)(p0 + i * 4);
        float4 c4 = *(const float4*)(p1 + i * 4);
        pk[2 * i] = pkbf((a.x + c4.x) * invl, (a.y + c4.y) * invl);
        pk[2 * i + 1] = pkbf((a.z + c4.z) * invl, (a.w + c4.w) * invl);
    }
#pragma unroll
    for (int j = 0; j < 4; j++) {
        uint4 ov;
        ov.x = pk[4 * j]; ov.y = pk[4 * j + 1];
        ov.z = pk[4 * j + 2]; ov.w = pk[4 * j + 3];
        *(uint4*)(hp + j * 8) = ov;   // 8 shorts per uint4 store (FIX)
    }
}

extern "C" void kernel_launch(void* const* d_in, const int* in_sizes, int n_in,
                              void* d_out, int out_size, void* d_ws,
                              size_t ws_size, hipStream_t stream) {
    const float* x    = (const float*)d_in[0];
    const int* maskp  = (const int*)d_in[1];
    const float* Wq   = (const float*)d_in[2];
    const float* bq   = (const float*)d_in[3];
    const float* Wk   = (const float*)d_in[4];
    const float* bk   = (const float*)d_in[5];
    const float* Wv   = (const float*)d_in[6];
    const float* bv   = (const float*)d_in[7];
    const float* Wo   = (const float*)d_in[8];
    const float* bo   = (const float*)d_in[9];
    const float* rb   = (const float*)d_in[10];
    float* out        = (float*)d_out;

    unsigned short* ws = (unsigned short*)d_ws;
    unsigned short* xb    = ws;                 // [0, 4M) elems
    unsigned short* wqkv  = ws + 4194304LL;     // [4M, 7M)
    unsigned short* wo_b  = ws + 7340032LL;     // [7M, 8M)
    unsigned short* qb    = ws + 8388608LL;     // [b,h,local,d]
    unsigned short* kb    = ws + 12582912LL;    // [b,h,local,d]
    unsigned short* vTb   = ws + 16777216LL;    // [b,h,d,local]
    unsigned short* hid   = ws + 20971520LL;    // [b*t][h*64+d] true rows
    unsigned* meta        = (unsigned*)(ws + 25165824LL);       // 4 u32
    unsigned* cidx        = (unsigned*)(ws + 25165856LL);       // 4224 u32
    unsigned short* vidx  = ws + 25174304LL;    // 4096 u16
    unsigned short* maskc = ws + 25178400LL;    // 4096 bf16
    float* pO   = (float*)(ws + 26214400LL);            // 8,388,608 f32
    float* pl   = (float*)(ws + 26214400LL + 16777216LL); // 131,072 f32

    cvt_kernel<<<12289, 256, 0, stream>>>(x, Wq, Wk, Wv, Wo, maskp, ws, cidx,
                                          vidx, maskc, meta, out);
    qkv_gemm<<<dim3(24, 64), 256, 0, stream>>>(xb, wqkv, bq, bk, bv, cidx,
                                               meta, qb, kb, vTb);
    attn_kernel<<<dim3(32, 16, 2), 256, 0, stream>>>(qb, kb, vTb, rb, maskc,
                                                     vidx, meta, pO, pl);
    combine_kernel<<<dim3(32, 16), 256, 0, stream>>>(pO, pl, vidx, meta, hid);
    out_gemm<<<dim3(16, 64), 256, 0, stream>>>(hid, wo_b, bo, cidx, meta,
                                               out);
}